// Round 1
// baseline (284.010 us; speedup 1.0000x reference)
//
#include <hip/hip_runtime.h>
#include <math.h>

// mLSTM cell, B=128, I=512, H=512.
// Outputs concatenated: h_t[128*512], C_t[128*512*512], m_t[128*512], n_t[128*512]
//
// ws layout (floats):
//   gates  : 128*3072 = 393216 @ 0
//   f_arr  : 65536 @ 393216
//   add_arr: 65536 @ 458752
//   o_arr  : 65536 @ 524288
//   invden : 128   @ 589824
// total ~2.36 MB

#define B_SZ   128
#define H_DIM  512
#define I_DIM  512
#define G6     3072           // 6*H
#define BH     65536          // B*H
#define CSZ    33554432       // B*H*H

// ---------------- Kernel 1: gates = x @ W^T + b ----------------
// c-tile = 256 (one column per thread), b-tile = 8 (register-blocked).
// Grid = 12 c-tiles * 16 b-tiles = 192 blocks.
// x addresses are wave-uniform -> scalar loads; W is per-thread sequential float4.
__global__ __launch_bounds__(256) void gemm_gates(
    const float* __restrict__ x, const float* __restrict__ W,
    const float* __restrict__ bias, float* __restrict__ gates) {
  const int tid = threadIdx.x;
  const int c   = (blockIdx.x % 12) * 256 + tid;   // [0, 3072)
  const int b0  = (blockIdx.x / 12) * 8;           // [0, 128) step 8

  float acc[8];
#pragma unroll
  for (int j = 0; j < 8; ++j) acc[j] = 0.0f;

  const float4* wrow = reinterpret_cast<const float4*>(W + (size_t)c * I_DIM);
  const float4* x4   = reinterpret_cast<const float4*>(x);

  for (int t4 = 0; t4 < I_DIM / 4; ++t4) {
    float4 wv = wrow[t4];
#pragma unroll
    for (int j = 0; j < 8; ++j) {
      float4 xv = x4[(b0 + j) * (I_DIM / 4) + t4];   // uniform addr -> s_load
      acc[j] += xv.x * wv.x + xv.y * wv.y + xv.z * wv.z + xv.w * wv.w;
    }
  }
  const float bi = bias[c];
#pragma unroll
  for (int j = 0; j < 8; ++j)
    gates[(size_t)(b0 + j) * G6 + c] = acc[j] + bi;   // coalesced over c
}

// ---------------- Kernel 2: pointwise gate math + nq reduction ----------------
// One block per batch row b. Writes m_t, n_t to out; f, add, o, 1/denom to ws.
__global__ __launch_bounds__(256) void gate_pointwise(
    const float* __restrict__ gates, const float* __restrict__ m_prev,
    const float* __restrict__ n_prev, float* __restrict__ out,
    float* __restrict__ f_arr, float* __restrict__ add_arr,
    float* __restrict__ o_arr, float* __restrict__ invden) {
  const int b   = blockIdx.x;
  const int tid = threadIdx.x;
  const float inv_sqrt_h = 0.044194173824159216f;  // 1/sqrt(512)

  const float* g = gates + (size_t)b * G6;
  float* out_m = out + BH + CSZ;
  float* out_n = out_m + BH;

  float local = 0.0f;
  for (int h = tid; h < H_DIM; h += 256) {
    const float ig = g[h];
    const float fg = g[512 + h];
    const float og = g[1024 + h];
    const float q  = g[1536 + h];
    const float k  = g[2048 + h];
    const float v  = g[2560 + h];

    const int   idx = b * H_DIM + h;
    const float kt  = inv_sqrt_h * k;
    const float ot  = 1.0f / (1.0f + expf(-og));
    const float mp  = m_prev[idx];
    const float npv = n_prev[idx];
    const float mt  = fmaxf(fg + mp, ig);
    const float it  = expf(ig - mt);
    const float ft  = expf(fg + mp - mt);    // arg <= 0, no overflow
    const float nt  = ft * npv + it * kt;

    out_m[idx]   = mt;
    out_n[idx]   = nt;
    f_arr[idx]   = ft;
    add_arr[idx] = it * v * kt;
    o_arr[idx]   = ot;
    local += nt * q;
  }

  __shared__ float red[256];
  red[tid] = local;
  __syncthreads();
#pragma unroll
  for (int s = 128; s > 0; s >>= 1) {
    if (tid < s) red[tid] += red[tid + s];
    __syncthreads();
  }
  if (tid == 0) {
    const float denom = fmaxf(fabsf(red[0]), 1e-6f);
    invden[b] = 1.0f / denom;
  }
}

// ---------------- Kernel 3: C_t = f*C_prev + add; Cq; h_t ----------------
// One wave per (b,i) row: stream 512 floats in/out as float4, fused dot with q[b,:].
__global__ __launch_bounds__(256) void update_C(
    const float* __restrict__ C_prev, const float* __restrict__ gates,
    const float* __restrict__ f_arr, const float* __restrict__ add_arr,
    const float* __restrict__ o_arr, const float* __restrict__ invden,
    float* __restrict__ out) {
  const int tid  = threadIdx.x;
  const int lane = tid & 63;
  const int r    = blockIdx.x * 4 + (tid >> 6);   // row in [0, 65536)
  const int b    = r >> 9;

  const float f = f_arr[r];
  const float a = add_arr[r];

  const float4* cp = reinterpret_cast<const float4*>(C_prev) + (size_t)r * 128;
  float4*       ct = reinterpret_cast<float4*>(out + BH) + (size_t)r * 128;
  const float4* q4 = reinterpret_cast<const float4*>(gates + (size_t)b * G6 + 1536);

  float cq = 0.0f;
#pragma unroll
  for (int itr = 0; itr < 2; ++itr) {
    const int idx = lane + 64 * itr;
    const float4 c  = cp[idx];
    const float4 qv = q4[idx];
    float4 o;
    o.x = f * c.x + a;
    o.y = f * c.y + a;
    o.z = f * c.z + a;
    o.w = f * c.w + a;
    ct[idx] = o;
    cq += o.x * qv.x + o.y * qv.y + o.z * qv.z + o.w * qv.w;
  }
#pragma unroll
  for (int off = 32; off > 0; off >>= 1)
    cq += __shfl_xor(cq, off, 64);
  if (lane == 0)
    out[r] = o_arr[r] * cq * invden[b];
}

extern "C" void kernel_launch(void* const* d_in, const int* in_sizes, int n_in,
                              void* d_out, int out_size, void* d_ws, size_t ws_size,
                              hipStream_t stream) {
  const float* x      = (const float*)d_in[0];
  // d_in[1] = h_prev (unused by the reference computation)
  const float* C_prev = (const float*)d_in[2];
  const float* m_prev = (const float*)d_in[3];
  const float* n_prev = (const float*)d_in[4];
  const float* W      = (const float*)d_in[5];
  const float* bias   = (const float*)d_in[6];

  float* out = (float*)d_out;
  float* ws  = (float*)d_ws;

  float* gates   = ws;
  float* f_arr   = ws + 393216;
  float* add_arr = f_arr + BH;
  float* o_arr   = add_arr + BH;
  float* invden  = o_arr + BH;

  gemm_gates<<<192, 256, 0, stream>>>(x, W, bias, gates);
  gate_pointwise<<<B_SZ, 256, 0, stream>>>(gates, m_prev, n_prev, out,
                                           f_arr, add_arr, o_arr, invden);
  update_C<<<BH / 4, 256, 0, stream>>>(C_prev, gates, f_arr, add_arr, o_arr,
                                       invden, out);
}